// Round 3
// baseline (613.921 us; speedup 1.0000x reference)
//
#include <hip/hip_runtime.h>

#define N_NODES 100000
#define N_EDGES 3200000
#define IN_CH 512
#define HID 16
#define OUT_CH 64

#define SCAN_BS 256
#define SCAN_CHUNK 1024                                   // 4 elements per thread
#define SCAN_NB ((N_NODES + SCAN_CHUNK - 1) / SCAN_CHUNK) // 98 (must be <= 128)

// XCD-ranged edge processing
#define N_XCD 8
#define RANGE (N_NODES / N_XCD)          // 12500 nodes per range
#define EB_BLOCKS_PER_GRP 128
#define EB_BS 256
#define EB_GRID (N_XCD * EB_BLOCKS_PER_GRP)   // 1024 blocks
#define EB_STRIDE (EB_BLOCKS_PER_GRP * EB_BS) // 32768 threads per group

typedef int v4i __attribute__((ext_vector_type(4)));

// ---------------- degree / scan / CSR ----------------

__global__ void k_init_deg(int* deg) {
    int i = blockIdx.x * blockDim.x + threadIdx.x;
    if (i < N_NODES) deg[i] = 1;  // self-loop
}

// XCD-ranged degree count: group g only counts dsts in [g*RANGE, (g+1)*RANGE)
// dst stream is nt (evict-first) so the deg[] reuse lines stay in L2.
__global__ void k_count(const int* __restrict__ dst, int* __restrict__ deg) {
    const int grp = blockIdx.x & (N_XCD - 1);   // round-robin -> same XCD per grp
    const int blk = blockIdx.x >> 3;
    const int lo = grp * RANGE;
    const int hi = lo + RANGE;
    const v4i* d4 = (const v4i*)dst;
    for (int i = blk * EB_BS + threadIdx.x; i < N_EDGES / 4; i += EB_STRIDE) {
        v4i v = __builtin_nontemporal_load(d4 + i);
        if (v.x >= lo && v.x < hi) atomicAdd(&deg[v.x], 1);
        if (v.y >= lo && v.y < hi) atomicAdd(&deg[v.y], 1);
        if (v.z >= lo && v.z < hi) atomicAdd(&deg[v.z], 1);
        if (v.w >= lo && v.w < hi) atomicAdd(&deg[v.w], 1);
    }
}

__global__ void k_scan_partial(const int* __restrict__ deg, int* __restrict__ partials) {
    __shared__ int sm[SCAN_BS];
    int tid = threadIdx.x;
    int base = blockIdx.x * SCAN_CHUNK;
    int s = 0;
    for (int j = 0; j < 4; ++j) {
        int i = base + j * SCAN_BS + tid;
        if (i < N_NODES) s += deg[i] - 1;   // edge count (excl self-loop)
    }
    sm[tid] = s;
    __syncthreads();
    for (int st = SCAN_BS / 2; st > 0; st >>= 1) {
        if (tid < st) sm[tid] += sm[tid + st];
        __syncthreads();
    }
    if (tid == 0) partials[blockIdx.x] = sm[0];
}

__global__ void k_scan_offsets(int* partials) {  // 1 block, 128 threads
    __shared__ int sm[128];
    int tid = threadIdx.x;
    int v = (tid < SCAN_NB) ? partials[tid] : 0;
    sm[tid] = v;
    __syncthreads();
    for (int st = 1; st < 128; st <<= 1) {
        int t = (tid >= st) ? sm[tid - st] : 0;
        __syncthreads();
        sm[tid] += t;
        __syncthreads();
    }
    if (tid < SCAN_NB) partials[tid] = sm[tid] - v;  // exclusive
}

__global__ void k_scan_final(const int* __restrict__ deg, const int* __restrict__ partials,
                             int* __restrict__ off, int* __restrict__ cur,
                             float* __restrict__ dinv) {
    __shared__ int sm[SCAN_BS];
    int tid = threadIdx.x;
    int base = blockIdx.x * SCAN_CHUNK + tid * 4;
    int v[4];
    int s = 0;
    for (int j = 0; j < 4; ++j) {
        int i = base + j;
        v[j] = (i < N_NODES) ? deg[i] - 1 : 0;
        s += v[j];
    }
    sm[tid] = s;
    __syncthreads();
    for (int st = 1; st < SCAN_BS; st <<= 1) {
        int t = (tid >= st) ? sm[tid - st] : 0;
        __syncthreads();
        sm[tid] += t;
        __syncthreads();
    }
    int run = partials[blockIdx.x] + sm[tid] - s;  // exclusive global prefix
    for (int j = 0; j < 4; ++j) {
        int i = base + j;
        if (i < N_NODES) {
            off[i] = run;
            cur[i] = run;
            dinv[i] = rsqrtf((float)deg[i]);
        }
        run += v[j];
    }
}

// XCD-ranged CSR scatter. dst/src streams are nt (evict-first) so the
// csr[] write-accumulation lines (1.6MB per group) stay L2-resident.
__global__ void k_build_csr(const int* __restrict__ src, const int* __restrict__ dst,
                            int* __restrict__ cur, int* __restrict__ csr) {
    const int grp = blockIdx.x & (N_XCD - 1);
    const int blk = blockIdx.x >> 3;
    const int lo = grp * RANGE;
    const int hi = lo + RANGE;
    const v4i* d4 = (const v4i*)dst;
    const v4i* s4 = (const v4i*)src;
    for (int i = blk * EB_BS + threadIdx.x; i < N_EDGES / 4; i += EB_STRIDE) {
        v4i v = __builtin_nontemporal_load(d4 + i);
        v4i sv = __builtin_nontemporal_load(s4 + i);
        if (v.x >= lo && v.x < hi) { int p = atomicAdd(&cur[v.x], 1); csr[p] = sv.x; }
        if (v.y >= lo && v.y < hi) { int p = atomicAdd(&cur[v.y], 1); csr[p] = sv.y; }
        if (v.z >= lo && v.z < hi) { int p = atomicAdd(&cur[v.z], 1); csr[p] = sv.z; }
        if (v.w >= lo && v.w < hi) { int p = atomicAdd(&cur[v.w], 1); csr[p] = sv.w; }
    }
}

// ---------------- GEMM1: y1 = (x @ W1) * dinv[n] ----------------

#define G1_BS 256
#define G1_NODES 128
#define G1_KT 64
#define G1_STRIDE (G1_KT + 4)   // 68 floats: 2-way bank access (free)

__global__ __launch_bounds__(G1_BS) void k_gemm1(const float* __restrict__ x,
                                                 const float* __restrict__ W1,
                                                 const float* __restrict__ dinv,
                                                 float* __restrict__ y1) {
    __shared__ float xt[G1_NODES * G1_STRIDE];  // 34816 B
    __shared__ float wt[G1_KT * HID];           // 4096 B
    const int tid = threadIdx.x;
    const int nl = tid >> 2;   // node slot 0..63
    const int cg = tid & 3;    // channel group (4 ch each)
    const int node_base = blockIdx.x * G1_NODES;

    float4 acc0 = {0.f, 0.f, 0.f, 0.f};
    float4 acc1 = {0.f, 0.f, 0.f, 0.f};

    for (int kt = 0; kt < IN_CH; kt += G1_KT) {
        __syncthreads();
        // x tile: 128 rows x 64 cols = 2048 float4, 8 per thread, coalesced
        for (int j = 0; j < 8; ++j) {
            int f4 = j * G1_BS + tid;
            int r = f4 >> 4;
            int c4 = f4 & 15;
            int gr = node_base + r;
            float4 v = {0.f, 0.f, 0.f, 0.f};
            if (gr < N_NODES)
                v = *(const float4*)(x + (size_t)gr * IN_CH + kt + c4 * 4);
            *(float4*)(xt + r * G1_STRIDE + c4 * 4) = v;
        }
        // W tile: 64 rows x 16 = 256 float4, 1 per thread
        {
            int r = tid >> 2;
            int c4 = tid & 3;
            *(float4*)(wt + r * HID + c4 * 4) =
                *(const float4*)(W1 + (size_t)(kt + r) * HID + c4 * 4);
        }
        __syncthreads();

        for (int kk = 0; kk < G1_KT; ++kk) {
            float xv0 = xt[nl * G1_STRIDE + kk];
            float xv1 = xt[(nl + 64) * G1_STRIDE + kk];
            float4 w = *(const float4*)(wt + kk * HID + cg * 4);
            acc0.x += xv0 * w.x; acc0.y += xv0 * w.y;
            acc0.z += xv0 * w.z; acc0.w += xv0 * w.w;
            acc1.x += xv1 * w.x; acc1.y += xv1 * w.y;
            acc1.z += xv1 * w.z; acc1.w += xv1 * w.w;
        }
    }

    int n0 = node_base + nl;
    int n1 = n0 + 64;
    if (n0 < N_NODES) {
        float dv = dinv[n0];
        float4 o = {acc0.x * dv, acc0.y * dv, acc0.z * dv, acc0.w * dv};
        *(float4*)(y1 + (size_t)n0 * HID + cg * 4) = o;
    }
    if (n1 < N_NODES) {
        float dv = dinv[n1];
        float4 o = {acc1.x * dv, acc1.y * dv, acc1.z * dv, acc1.w * dv};
        *(float4*)(y1 + (size_t)n1 * HID + cg * 4) = o;
    }
}

// ---------------- layer1 aggregation: y2 = relu(dinv*(agg+y1)+b1)*dinv --------

__global__ void k_layer1(const float* __restrict__ y1, const int* __restrict__ off,
                         const int* __restrict__ deg, const int* __restrict__ csr,
                         const float* __restrict__ dinv, const float* __restrict__ b1,
                         float* __restrict__ y2) {
    int t = blockIdx.x * blockDim.x + threadIdx.x;  // grid exactly N_NODES*16
    int n = t >> 4;
    int c = t & 15;
    int base = off[n];
    int cnt = deg[n] - 1;
    float acc = 0.f;
    for (int p = 0; p < cnt; ++p) {
        int s = __builtin_nontemporal_load(csr + base + p);  // stream, read-once
        acc += y1[s * HID + c];
    }
    float dv = dinv[n];
    float h = dv * (acc + y1[n * HID + c]) + b1[c];
    h = fmaxf(h, 0.f);
    y2[n * HID + c] = h * dv;
}

// ---------------- layer2 aggregation fused with GEMM2 + bias ----------------

__global__ void k_layer2(const float* __restrict__ y2, const int* __restrict__ off,
                         const int* __restrict__ deg, const int* __restrict__ csr,
                         const float* __restrict__ dinv, const float* __restrict__ W2,
                         const float* __restrict__ b2, float* __restrict__ out) {
    __shared__ float w2[HID * OUT_CH];  // 4 KB
    __shared__ float bs[OUT_CH];
    int tid = threadIdx.x;
    for (int j = tid; j < HID * OUT_CH; j += blockDim.x) w2[j] = W2[j];
    if (tid < OUT_CH) bs[tid] = b2[tid];
    __syncthreads();

    int t = blockIdx.x * blockDim.x + tid;  // grid exactly N_NODES*16
    int n = t >> 4;
    int c = t & 15;
    int base = off[n];
    int cnt = deg[n] - 1;
    float acc = 0.f;
    for (int p = 0; p < cnt; ++p) {
        int s = __builtin_nontemporal_load(csr + base + p);  // stream, read-once
        acc += y2[s * HID + c];
    }
    float z = dinv[n] * (acc + y2[n * HID + c]);  // this lane's channel of agg

    // each lane computes 4 of the 64 outputs: o = c*4 .. c*4+3
    float4 o = {bs[c * 4 + 0], bs[c * 4 + 1], bs[c * 4 + 2], bs[c * 4 + 3]};
    int lane = tid & 63;
    int gsub = lane >> 4;  // which 16-lane node-group within the wave
    for (int cc = 0; cc < HID; ++cc) {
        float zz = __shfl(z, gsub * 16 + cc, 64);
        float4 w = *(const float4*)(w2 + cc * OUT_CH + c * 4);
        o.x += zz * w.x; o.y += zz * w.y; o.z += zz * w.z; o.w += zz * w.w;
    }
    *(float4*)(out + (size_t)n * OUT_CH + c * 4) = o;
}

// ---------------- launch ----------------

extern "C" void kernel_launch(void* const* d_in, const int* in_sizes, int n_in,
                              void* d_out, int out_size, void* d_ws, size_t ws_size,
                              hipStream_t stream) {
    const float* x  = (const float*)d_in[0];
    const int*   ei = (const int*)d_in[1];
    const float* W1 = (const float*)d_in[2];
    const float* b1 = (const float*)d_in[3];
    const float* W2 = (const float*)d_in[4];
    const float* b2 = (const float*)d_in[5];
    float* out = (float*)d_out;

    const int* src = ei;            // edge_index[0]
    const int* dst = ei + N_EDGES;  // edge_index[1]

    char* w = (char*)d_ws;
    const size_t SN = 409600;  // per-N-array slot (100K*4 rounded up)
    int*   deg      = (int*)(w);
    float* dinv     = (float*)(w + SN);
    int*   off      = (int*)(w + 2 * SN);
    int*   cur      = (int*)(w + 3 * SN);
    int*   partials = (int*)(w + 4 * SN);
    int*   csr      = (int*)(w + 5 * SN);                        // 12.8 MB
    float* y1       = (float*)(w + 5 * SN + 13107200);           // 6.4 MB
    float* y2       = (float*)(w + 5 * SN + 13107200 + 6553600); // 6.4 MB
    // total ~28.3 MB of d_ws

    k_init_deg<<<(N_NODES + 255) / 256, 256, 0, stream>>>(deg);
    k_count<<<EB_GRID, EB_BS, 0, stream>>>(dst, deg);
    k_scan_partial<<<SCAN_NB, SCAN_BS, 0, stream>>>(deg, partials);
    k_scan_offsets<<<1, 128, 0, stream>>>(partials);
    k_scan_final<<<SCAN_NB, SCAN_BS, 0, stream>>>(deg, partials, off, cur, dinv);
    k_build_csr<<<EB_GRID, EB_BS, 0, stream>>>(src, dst, cur, csr);
    k_gemm1<<<(N_NODES + G1_NODES - 1) / G1_NODES, G1_BS, 0, stream>>>(x, W1, dinv, y1);
    k_layer1<<<(N_NODES * HID) / 256, 256, 0, stream>>>(y1, off, deg, csr, dinv, b1, y2);
    k_layer2<<<(N_NODES * HID) / 256, 256, 0, stream>>>(y2, off, deg, csr, dinv, W2, b2, out);
}

// Round 4
// 444.655 us; speedup vs baseline: 1.3807x; 1.3807x over previous
//
#include <hip/hip_runtime.h>

#define N_NODES 100000
#define N_EDGES 3200000
#define IN_CH 512
#define HID 16
#define OUT_CH 64

#define SCAN_BS 256
#define SCAN_CHUNK 1024                                   // 4 elements per thread
#define SCAN_NB ((N_NODES + SCAN_CHUNK - 1) / SCAN_CHUNK) // 98 (must be <= 128)

// XCD-ranged edge processing
#define N_XCD 8
#define RANGE (N_NODES / N_XCD)          // 12500 nodes per range
#define EB_BLOCKS_PER_GRP 256
#define EB_BS 256
#define EB_GRID (N_XCD * EB_BLOCKS_PER_GRP)   // 2048 blocks -> 32 waves/CU
#define EB_STRIDE (EB_BLOCKS_PER_GRP * EB_BS) // 65536 threads per group

typedef int v4i __attribute__((ext_vector_type(4)));

// ---------------- degree / scan / CSR ----------------

__global__ void k_init_deg(int* deg) {
    int i = blockIdx.x * blockDim.x + threadIdx.x;
    if (i < N_NODES) deg[i] = 1;  // self-loop
}

// XCD-ranged degree count: group g only counts dsts in [g*RANGE, (g+1)*RANGE)
// dst stream is nt (evict-first) so the deg[] reuse lines stay in L2.
__global__ void k_count(const int* __restrict__ dst, int* __restrict__ deg) {
    const int grp = blockIdx.x & (N_XCD - 1);   // round-robin -> same XCD per grp
    const int blk = blockIdx.x >> 3;
    const int lo = grp * RANGE;
    const int hi = lo + RANGE;
    const v4i* d4 = (const v4i*)dst;
    for (int i = blk * EB_BS + threadIdx.x; i < N_EDGES / 4; i += EB_STRIDE) {
        v4i v = __builtin_nontemporal_load(d4 + i);
        if (v.x >= lo && v.x < hi) atomicAdd(&deg[v.x], 1);
        if (v.y >= lo && v.y < hi) atomicAdd(&deg[v.y], 1);
        if (v.z >= lo && v.z < hi) atomicAdd(&deg[v.z], 1);
        if (v.w >= lo && v.w < hi) atomicAdd(&deg[v.w], 1);
    }
}

__global__ void k_scan_partial(const int* __restrict__ deg, int* __restrict__ partials) {
    __shared__ int sm[SCAN_BS];
    int tid = threadIdx.x;
    int base = blockIdx.x * SCAN_CHUNK;
    int s = 0;
    for (int j = 0; j < 4; ++j) {
        int i = base + j * SCAN_BS + tid;
        if (i < N_NODES) s += deg[i] - 1;   // edge count (excl self-loop)
    }
    sm[tid] = s;
    __syncthreads();
    for (int st = SCAN_BS / 2; st > 0; st >>= 1) {
        if (tid < st) sm[tid] += sm[tid + st];
        __syncthreads();
    }
    if (tid == 0) partials[blockIdx.x] = sm[0];
}

__global__ void k_scan_offsets(int* partials) {  // 1 block, 128 threads
    __shared__ int sm[128];
    int tid = threadIdx.x;
    int v = (tid < SCAN_NB) ? partials[tid] : 0;
    sm[tid] = v;
    __syncthreads();
    for (int st = 1; st < 128; st <<= 1) {
        int t = (tid >= st) ? sm[tid - st] : 0;
        __syncthreads();
        sm[tid] += t;
        __syncthreads();
    }
    if (tid < SCAN_NB) partials[tid] = sm[tid] - v;  // exclusive
}

__global__ void k_scan_final(const int* __restrict__ deg, const int* __restrict__ partials,
                             int* __restrict__ off, int* __restrict__ cur,
                             float* __restrict__ dinv) {
    __shared__ int sm[SCAN_BS];
    int tid = threadIdx.x;
    int base = blockIdx.x * SCAN_CHUNK + tid * 4;
    int v[4];
    int s = 0;
    for (int j = 0; j < 4; ++j) {
        int i = base + j;
        v[j] = (i < N_NODES) ? deg[i] - 1 : 0;
        s += v[j];
    }
    sm[tid] = s;
    __syncthreads();
    for (int st = 1; st < SCAN_BS; st <<= 1) {
        int t = (tid >= st) ? sm[tid - st] : 0;
        __syncthreads();
        sm[tid] += t;
        __syncthreads();
    }
    int run = partials[blockIdx.x] + sm[tid] - s;  // exclusive global prefix
    for (int j = 0; j < 4; ++j) {
        int i = base + j;
        if (i < N_NODES) {
            off[i] = run;
            cur[i] = run;
            dinv[i] = rsqrtf((float)deg[i]);
        }
        run += v[j];
    }
}

// XCD-ranged CSR scatter. dst/src streams are nt (evict-first) so the
// csr[] write-accumulation lines (1.6MB per group) stay L2-resident.
__global__ void k_build_csr(const int* __restrict__ src, const int* __restrict__ dst,
                            int* __restrict__ cur, int* __restrict__ csr) {
    const int grp = blockIdx.x & (N_XCD - 1);
    const int blk = blockIdx.x >> 3;
    const int lo = grp * RANGE;
    const int hi = lo + RANGE;
    const v4i* d4 = (const v4i*)dst;
    const v4i* s4 = (const v4i*)src;
    for (int i = blk * EB_BS + threadIdx.x; i < N_EDGES / 4; i += EB_STRIDE) {
        v4i v = __builtin_nontemporal_load(d4 + i);
        v4i sv = __builtin_nontemporal_load(s4 + i);
        if (v.x >= lo && v.x < hi) { int p = atomicAdd(&cur[v.x], 1); csr[p] = sv.x; }
        if (v.y >= lo && v.y < hi) { int p = atomicAdd(&cur[v.y], 1); csr[p] = sv.y; }
        if (v.z >= lo && v.z < hi) { int p = atomicAdd(&cur[v.z], 1); csr[p] = sv.z; }
        if (v.w >= lo && v.w < hi) { int p = atomicAdd(&cur[v.w], 1); csr[p] = sv.w; }
    }
}

// ---------------- GEMM1: y1 = (x @ W1) * dinv[n] ----------------

#define G1_BS 256
#define G1_NODES 128
#define G1_KT 64
#define G1_STRIDE (G1_KT + 4)   // 68 floats: 2-way bank access (free)

__global__ __launch_bounds__(G1_BS) void k_gemm1(const float* __restrict__ x,
                                                 const float* __restrict__ W1,
                                                 const float* __restrict__ dinv,
                                                 float* __restrict__ y1) {
    __shared__ float xt[G1_NODES * G1_STRIDE];  // 34816 B
    __shared__ float wt[G1_KT * HID];           // 4096 B
    const int tid = threadIdx.x;
    const int nl = tid >> 2;   // node slot 0..63
    const int cg = tid & 3;    // channel group (4 ch each)
    const int node_base = blockIdx.x * G1_NODES;

    float4 acc0 = {0.f, 0.f, 0.f, 0.f};
    float4 acc1 = {0.f, 0.f, 0.f, 0.f};

    for (int kt = 0; kt < IN_CH; kt += G1_KT) {
        __syncthreads();
        // x tile: 128 rows x 64 cols = 2048 float4, 8 per thread, coalesced
        for (int j = 0; j < 8; ++j) {
            int f4 = j * G1_BS + tid;
            int r = f4 >> 4;
            int c4 = f4 & 15;
            int gr = node_base + r;
            float4 v = {0.f, 0.f, 0.f, 0.f};
            if (gr < N_NODES)
                v = *(const float4*)(x + (size_t)gr * IN_CH + kt + c4 * 4);
            *(float4*)(xt + r * G1_STRIDE + c4 * 4) = v;
        }
        // W tile: 64 rows x 16 = 256 float4, 1 per thread
        {
            int r = tid >> 2;
            int c4 = tid & 3;
            *(float4*)(wt + r * HID + c4 * 4) =
                *(const float4*)(W1 + (size_t)(kt + r) * HID + c4 * 4);
        }
        __syncthreads();

        for (int kk = 0; kk < G1_KT; ++kk) {
            float xv0 = xt[nl * G1_STRIDE + kk];
            float xv1 = xt[(nl + 64) * G1_STRIDE + kk];
            float4 w = *(const float4*)(wt + kk * HID + cg * 4);
            acc0.x += xv0 * w.x; acc0.y += xv0 * w.y;
            acc0.z += xv0 * w.z; acc0.w += xv0 * w.w;
            acc1.x += xv1 * w.x; acc1.y += xv1 * w.y;
            acc1.z += xv1 * w.z; acc1.w += xv1 * w.w;
        }
    }

    int n0 = node_base + nl;
    int n1 = n0 + 64;
    if (n0 < N_NODES) {
        float dv = dinv[n0];
        float4 o = {acc0.x * dv, acc0.y * dv, acc0.z * dv, acc0.w * dv};
        *(float4*)(y1 + (size_t)n0 * HID + cg * 4) = o;
    }
    if (n1 < N_NODES) {
        float dv = dinv[n1];
        float4 o = {acc1.x * dv, acc1.y * dv, acc1.z * dv, acc1.w * dv};
        *(float4*)(y1 + (size_t)n1 * HID + cg * 4) = o;
    }
}

// ---------------- layer1 aggregation: y2 = relu(dinv*(agg+y1)+b1)*dinv --------
// 4-way unrolled gather: 4 outstanding load-dependent-loads per thread (MLP).

__global__ void k_layer1(const float* __restrict__ y1, const int* __restrict__ off,
                         const int* __restrict__ deg, const int* __restrict__ csr,
                         const float* __restrict__ dinv, const float* __restrict__ b1,
                         float* __restrict__ y2) {
    int t = blockIdx.x * blockDim.x + threadIdx.x;  // grid exactly N_NODES*16
    int n = t >> 4;
    int c = t & 15;
    int base = off[n];
    int cnt = deg[n] - 1;
    float a0 = 0.f, a1 = 0.f, a2 = 0.f, a3 = 0.f;
    int p = 0;
    for (; p + 4 <= cnt; p += 4) {
        int s0 = csr[base + p + 0];
        int s1 = csr[base + p + 1];
        int s2 = csr[base + p + 2];
        int s3 = csr[base + p + 3];
        a0 += y1[s0 * HID + c];
        a1 += y1[s1 * HID + c];
        a2 += y1[s2 * HID + c];
        a3 += y1[s3 * HID + c];
    }
    for (; p < cnt; ++p) a0 += y1[csr[base + p] * HID + c];
    float acc = (a0 + a1) + (a2 + a3);
    float dv = dinv[n];
    float h = dv * (acc + y1[n * HID + c]) + b1[c];
    h = fmaxf(h, 0.f);
    y2[n * HID + c] = h * dv;
}

// ---------------- layer2 aggregation fused with GEMM2 + bias ----------------

__global__ void k_layer2(const float* __restrict__ y2, const int* __restrict__ off,
                         const int* __restrict__ deg, const int* __restrict__ csr,
                         const float* __restrict__ dinv, const float* __restrict__ W2,
                         const float* __restrict__ b2, float* __restrict__ out) {
    __shared__ float w2[HID * OUT_CH];  // 4 KB
    __shared__ float bs[OUT_CH];
    int tid = threadIdx.x;
    for (int j = tid; j < HID * OUT_CH; j += blockDim.x) w2[j] = W2[j];
    if (tid < OUT_CH) bs[tid] = b2[tid];
    __syncthreads();

    int t = blockIdx.x * blockDim.x + tid;  // grid exactly N_NODES*16
    int n = t >> 4;
    int c = t & 15;
    int base = off[n];
    int cnt = deg[n] - 1;
    float a0 = 0.f, a1 = 0.f, a2 = 0.f, a3 = 0.f;
    int p = 0;
    for (; p + 4 <= cnt; p += 4) {
        int s0 = csr[base + p + 0];
        int s1 = csr[base + p + 1];
        int s2 = csr[base + p + 2];
        int s3 = csr[base + p + 3];
        a0 += y2[s0 * HID + c];
        a1 += y2[s1 * HID + c];
        a2 += y2[s2 * HID + c];
        a3 += y2[s3 * HID + c];
    }
    for (; p < cnt; ++p) a0 += y2[csr[base + p] * HID + c];
    float acc = (a0 + a1) + (a2 + a3);
    float z = dinv[n] * (acc + y2[n * HID + c]);  // this lane's channel of agg

    // each lane computes 4 of the 64 outputs: o = c*4 .. c*4+3
    float4 o = {bs[c * 4 + 0], bs[c * 4 + 1], bs[c * 4 + 2], bs[c * 4 + 3]};
    int lane = tid & 63;
    int gsub = lane >> 4;  // which 16-lane node-group within the wave
    for (int cc = 0; cc < HID; ++cc) {
        float zz = __shfl(z, gsub * 16 + cc, 64);
        float4 w = *(const float4*)(w2 + cc * OUT_CH + c * 4);
        o.x += zz * w.x; o.y += zz * w.y; o.z += zz * w.z; o.w += zz * w.w;
    }
    *(float4*)(out + (size_t)n * OUT_CH + c * 4) = o;
}

// ---------------- launch ----------------

extern "C" void kernel_launch(void* const* d_in, const int* in_sizes, int n_in,
                              void* d_out, int out_size, void* d_ws, size_t ws_size,
                              hipStream_t stream) {
    const float* x  = (const float*)d_in[0];
    const int*   ei = (const int*)d_in[1];
    const float* W1 = (const float*)d_in[2];
    const float* b1 = (const float*)d_in[3];
    const float* W2 = (const float*)d_in[4];
    const float* b2 = (const float*)d_in[5];
    float* out = (float*)d_out;

    const int* src = ei;            // edge_index[0]
    const int* dst = ei + N_EDGES;  // edge_index[1]

    char* w = (char*)d_ws;
    const size_t SN = 409600;  // per-N-array slot (100K*4 rounded up)
    int*   deg      = (int*)(w);
    float* dinv     = (float*)(w + SN);
    int*   off      = (int*)(w + 2 * SN);
    int*   cur      = (int*)(w + 3 * SN);
    int*   partials = (int*)(w + 4 * SN);
    int*   csr      = (int*)(w + 5 * SN);                        // 12.8 MB
    float* y1       = (float*)(w + 5 * SN + 13107200);           // 6.4 MB
    float* y2       = (float*)(w + 5 * SN + 13107200 + 6553600); // 6.4 MB
    // total ~28.3 MB of d_ws

    k_init_deg<<<(N_NODES + 255) / 256, 256, 0, stream>>>(deg);
    k_count<<<EB_GRID, EB_BS, 0, stream>>>(dst, deg);
    k_scan_partial<<<SCAN_NB, SCAN_BS, 0, stream>>>(deg, partials);
    k_scan_offsets<<<1, 128, 0, stream>>>(partials);
    k_scan_final<<<SCAN_NB, SCAN_BS, 0, stream>>>(deg, partials, off, cur, dinv);
    k_build_csr<<<EB_GRID, EB_BS, 0, stream>>>(src, dst, cur, csr);
    k_gemm1<<<(N_NODES + G1_NODES - 1) / G1_NODES, G1_BS, 0, stream>>>(x, W1, dinv, y1);
    k_layer1<<<(N_NODES * HID) / 256, 256, 0, stream>>>(y1, off, deg, csr, dinv, b1, y2);
    k_layer2<<<(N_NODES * HID) / 256, 256, 0, stream>>>(y2, off, deg, csr, dinv, W2, b2, out);
}